// Round 16
// baseline (187.515 us; speedup 1.0000x reference)
//
#include <hip/hip_runtime.h>
#include <hip/hip_bf16.h>

#define OUT_F 4096
#define IN_F 4096
#define MROWS 2048            // 4*512 batch rows
#define FFT_N 4096
#define HCOLS 2049            // Hermitian-reduced column count
#define SHARDS 8              // bucket shards (bid&7 ~ XCD id under round-robin dispatch)
#define SCAP 128              // capacity per (v,shard): mean 25.6, P(>128) ~ e^-80

typedef short bf16x8 __attribute__((ext_vector_type(8)));
typedef float f32x4 __attribute__((ext_vector_type(4)));

// ====== bucket build (+ fused x-cast): blocks [0,sb) scatter, [sb,sb+512) cast ======
// 8-way sharded buckets: counter (v,shard) is updated only by blocks with
// bid&7==shard (~same XCD) -> ~26 L2-local RMWs per counter instead of ~205
// cross-XCD ping-pongs. One padded counter per 64-B line.
__global__ void bucket_scatter_kernel(const int* __restrict__ idx, const float* __restrict__ re,
                                      const float* __restrict__ im, unsigned* __restrict__ pos,
                                      uint4* __restrict__ bkt, int nnz, int sb,
                                      const float4* __restrict__ x, ushort4* __restrict__ xb) {
    const int bid = blockIdx.x;
    const int t = threadIdx.x;
    if (bid >= sb) {                                  // cast branch (independent work)
        const int n4 = MROWS * IN_F / 4;
        const int stride = 512 * 256;
        for (int i = (bid - sb) * 256 + t; i < n4; i += stride) {
            float4 v = x[i];
            __hip_bfloat16 a = __float2bfloat16(v.x);
            __hip_bfloat16 b = __float2bfloat16(v.y);
            __hip_bfloat16 c = __float2bfloat16(v.z);
            __hip_bfloat16 d = __float2bfloat16(v.w);
            ushort4 o;
            o.x = *reinterpret_cast<unsigned short*>(&a);
            o.y = *reinterpret_cast<unsigned short*>(&b);
            o.z = *reinterpret_cast<unsigned short*>(&c);
            o.w = *reinterpret_cast<unsigned short*>(&d);
            xb[i] = o;
        }
        return;
    }
    const unsigned shard = (unsigned)bid & 7u;
    int k = bid * 256 + t;
    if (k < nnz) {
        int id = idx[k];
        unsigned v = (unsigned)id & (IN_F - 1);
        unsigned u = (unsigned)id >> 12;
        unsigned cell = (v << 3) | shard;
        unsigned p = atomicAdd(&pos[cell << 4], 1u);   // 1 counter per 64-B line
        if (p < SCAP) {
            bkt[cell * SCAP + p] = make_uint4(((unsigned)k << 12) | u,
                                              __float_as_uint(re[k]),
                                              __float_as_uint(im[k]), 0u);
        }
    }
}

// ================= 16-pt inverse FFT building blocks =================
__device__ __forceinline__ float2 cmul(float2 a, float2 b) {
    return make_float2(a.x * b.x - a.y * b.y, a.x * b.y + a.y * b.x);
}
__device__ __forceinline__ void bflyw(float2& a, float2& b, float wr, float wi) {
    float tr = b.x * wr - b.y * wi;
    float ti = b.x * wi + b.y * wr;
    b.x = a.x - tr; b.y = a.y - ti;
    a.x += tr; a.y += ti;
}
__device__ __forceinline__ void bfly1(float2& a, float2& b) {   // w = 1
    float tr = b.x, ti = b.y;
    b.x = a.x - tr; b.y = a.y - ti;
    a.x += tr; a.y += ti;
}
__device__ __forceinline__ void bflyI(float2& a, float2& b) {   // w = +i
    float tr = -b.y, ti = b.x;
    b.x = a.x - tr; b.y = a.y - ti;
    a.x += tr; a.y += ti;
}

#define C8f  0.70710678118654752f
#define C16f 0.92387953251128676f
#define S16f 0.38268343236508977f

// inverse 16-pt FFT (+i convention). Input in bit-reversed slots, output natural.
__device__ __forceinline__ void fft16(float2 r[16]) {
    bfly1(r[0], r[1]);  bfly1(r[2], r[3]);  bfly1(r[4], r[5]);   bfly1(r[6], r[7]);
    bfly1(r[8], r[9]);  bfly1(r[10], r[11]); bfly1(r[12], r[13]); bfly1(r[14], r[15]);
    bfly1(r[0], r[2]);  bflyI(r[1], r[3]);
    bfly1(r[4], r[6]);  bflyI(r[5], r[7]);
    bfly1(r[8], r[10]); bflyI(r[9], r[11]);
    bfly1(r[12], r[14]); bflyI(r[13], r[15]);
    bfly1(r[0], r[4]);  bflyw(r[1], r[5], C8f, C8f);  bflyI(r[2], r[6]);  bflyw(r[3], r[7], -C8f, C8f);
    bfly1(r[8], r[12]); bflyw(r[9], r[13], C8f, C8f); bflyI(r[10], r[14]); bflyw(r[11], r[15], -C8f, C8f);
    bfly1(r[0], r[8]);
    bflyw(r[1], r[9],  C16f, S16f);
    bflyw(r[2], r[10], C8f,  C8f);
    bflyw(r[3], r[11], S16f, C16f);
    bflyI(r[4], r[12]);
    bflyw(r[5], r[13], -S16f, C16f);
    bflyw(r[6], r[14], -C8f,  C8f);
    bflyw(r[7], r[15], -C16f, S16f);
}

// depth-4 tree twiddle: r[k] *= w^k, w = exp(i*ang).
__device__ __forceinline__ void twiddle16(float2 r[16], float ang) {
    float s, c;
    __sincosf(ang, &s, &c);
    float2 w1 = make_float2(c, s);
    float2 w2 = cmul(w1, w1), w4 = cmul(w2, w2), w8 = cmul(w4, w4);
    float2 cur[16];
    cur[1] = w1; cur[2] = w2; cur[3] = cmul(w2, w1);
    cur[4] = w4; cur[5] = cmul(w4, w1); cur[6] = cmul(w4, w2); cur[7] = cmul(w4, cur[3]);
    #pragma unroll
    for (int k = 0; k < 8; ++k) cur[8 + k] = (k == 0) ? w8 : cmul(w8, cur[k]);
    #pragma unroll
    for (int k = 1; k < 16; ++k) r[k] = cmul(r[k], cur[k]);
}

// LDS XOR swizzle: bijective on [0,4096)
__device__ __forceinline__ int swz(int a) { return a ^ ((a >> 5) & 31); }

__device__ __forceinline__ unsigned packbf2(float re, float im) {
    __hip_bfloat16 r = __float2bfloat16(re), i = __float2bfloat16(im);
    unsigned short rb = *reinterpret_cast<unsigned short*>(&r);
    unsigned short ib = *reinterpret_cast<unsigned short*>(&i);
    return ((unsigned)ib << 16) | (unsigned)rb;
}
__device__ __forceinline__ float bflo(unsigned p) { return __uint_as_float(p << 16); }
__device__ __forceinline__ float bfhi(unsigned p) { return __uint_as_float(p & 0xffff0000u); }

__device__ __forceinline__ void fft4096_lds(float* bre, float* bim, int t, float2 r[16],
                                            const int* rv) {
    // ---- phase 1: 16-pt over n1, column n2 = t ----
    #pragma unroll
    for (int n1 = 0; n1 < 16; ++n1) {
        int a = swz(256 * n1 + t);
        r[rv[n1]] = make_float2(bre[a], bim[a]);
    }
    fft16(r);
    twiddle16(r, (float)t * 1.5339807878856412e-3f);   // 2*pi/4096
    #pragma unroll
    for (int k = 0; k < 16; ++k) {
        int a = swz(256 * k + t);
        bre[a] = r[k].x; bim[a] = r[k].y;
    }
    __syncthreads();

    // ---- phase 2 ----
    const int k1 = t >> 4;
    const int lo = t & 15;
    const int base2 = 256 * k1 + lo;
    #pragma unroll
    for (int m1 = 0; m1 < 16; ++m1) {
        int a = swz(base2 + 16 * m1);
        r[rv[m1]] = make_float2(bre[a], bim[a]);
    }
    fft16(r);
    twiddle16(r, (float)lo * 2.45436926061702596e-2f); // 2*pi/256
    #pragma unroll
    for (int k = 0; k < 16; ++k) {
        int a = swz(base2 + 16 * k);
        bre[a] = r[k].x; bim[a] = r[k].y;
    }
    __syncthreads();

    // ---- phase 3 ----
    const int base3 = 256 * k1 + 16 * lo;
    #pragma unroll
    for (int m = 0; m < 16; ++m) {
        int a = swz(base3 + m);
        r[rv[m]] = make_float2(bre[a], bim[a]);
    }
    fft16(r);
    __syncthreads();   // all reads done before digit-swap scatter overwrites
}

// ---------------- pass 1: Hermitian-symmetrized scatter + 4096-pt IFFT over u ----------------
// Gathers 8 shards per bucket (each count <= SCAP <= 256 -> one conditional
// coalesced uint4 load per shard; fully unrolled -> static register indexing).
__global__ void __launch_bounds__(256) ifft_pass1_kernel(const unsigned* __restrict__ pos,
                                                         const uint4* __restrict__ bkt,
                                                         unsigned* __restrict__ outp) {
    __shared__ float bre[FFT_N];
    __shared__ float bim[FFT_N];
    unsigned* kwin  = (unsigned*)bre;   // alias: dead before bre is zero-filled
    unsigned* kwin2 = (unsigned*)bim;
    const int t = threadIdx.x;
    const int vp = blockIdx.x;                 // 0..2048
    const int bd = vp;
    const int bm = (4096 - vp) & 4095;         // mirror bucket (== bd for vp=0,2048)
    const bool sameb = (bm == bd);

    unsigned pkD[SHARDS], pkM[SHARDS];
    float2 wvD[SHARDS], wvM[SHARDS];
    bool vldD[SHARDS], vldM[SHARDS], winD[SHARDS], winM[SHARDS];
    #pragma unroll
    for (int s = 0; s < SHARDS; ++s) {
        const unsigned cellD = ((unsigned)bd << 3) | (unsigned)s;
        const unsigned cD = min(pos[cellD << 4], (unsigned)SCAP);
        vldD[s] = ((unsigned)t < cD);
        uint4 eD = vldD[s] ? bkt[(size_t)cellD * SCAP + t] : make_uint4(0u, 0u, 0u, 0u);
        pkD[s] = eD.x;
        wvD[s] = make_float2(__uint_as_float(eD.y), __uint_as_float(eD.z));
        const unsigned cellM = ((unsigned)bm << 3) | (unsigned)s;
        const unsigned cM = min(pos[cellM << 4], (unsigned)SCAP);
        vldM[s] = ((unsigned)t < cM);
        uint4 eM = vldM[s] ? bkt[(size_t)cellM * SCAP + t] : make_uint4(0u, 0u, 0u, 0u);
        pkM[s] = eM.x;
        wvM[s] = make_float2(__uint_as_float(eM.y), __uint_as_float(eM.z));
    }

    // single-round winner resolution: D -> kwin, M -> kwin2 (vectorized zero)
    {
        uint4 z4 = make_uint4(0u, 0u, 0u, 0u);
        uint4* kz1 = (uint4*)kwin;
        uint4* kz2 = (uint4*)kwin2;
        #pragma unroll
        for (int j = 0; j < 4; ++j) { kz1[t + j * 256] = z4; kz2[t + j * 256] = z4; }
    }
    __syncthreads();
    #pragma unroll
    for (int s = 0; s < SHARDS; ++s)
        if (vldD[s]) atomicMax(&kwin[pkD[s] & 4095u], pkD[s]);
    #pragma unroll
    for (int s = 0; s < SHARDS; ++s)
        if (vldM[s]) atomicMax(&kwin2[pkM[s] & 4095u], pkM[s]);
    __syncthreads();
    #pragma unroll
    for (int s = 0; s < SHARDS; ++s)
        winD[s] = vldD[s] && (kwin[pkD[s] & 4095u] == pkD[s]);
    #pragma unroll
    for (int s = 0; s < SHARDS; ++s)
        winM[s] = vldM[s] && ((sameb ? kwin : kwin2)[pkM[s] & 4095u] == pkM[s]);
    __syncthreads();   // all kwin reads done before bre/bim overwrite

    {
        float4 z4 = make_float4(0.f, 0.f, 0.f, 0.f);
        float4* z1 = (float4*)bre;
        float4* z2 = (float4*)bim;
        #pragma unroll
        for (int j = 0; j < 4; ++j) { z1[t + j * 256] = z4; z2[t + j * 256] = z4; }
    }
    __syncthreads();
    // merged scatter: D adds 0.5*val at u, M adds 0.5*conj(val) at 4096-u2.
    // <=1 D-adder and <=1 M-adder per cell; commutative adds -> deterministic.
    #pragma unroll
    for (int s = 0; s < SHARDS; ++s)
        if (winD[s]) {
            int a = swz((int)(pkD[s] & 4095u));
            atomicAdd(&bre[a], 0.5f * wvD[s].x);
            atomicAdd(&bim[a], 0.5f * wvD[s].y);
        }
    #pragma unroll
    for (int s = 0; s < SHARDS; ++s)
        if (winM[s]) {
            int u2 = (int)(pkM[s] & 4095u);
            int a = swz((4096 - u2) & 4095);
            atomicAdd(&bre[a], 0.5f * wvM[s].x);
            atomicAdd(&bim[a], -0.5f * wvM[s].y);
        }
    __syncthreads();

    const int rv[16] = {0, 8, 4, 12, 2, 10, 6, 14, 1, 9, 5, 13, 3, 11, 7, 15};
    float2 r[16];
    fft4096_lds(bre, bim, t, r, rv);

    const float scale = 1.0f / 4096.0f;
    const int k1 = t >> 4, lo = t & 15;
    const int outb = k1 + 16 * lo;
    #pragma unroll
    for (int j2 = 0; j2 < 16; ++j2) {
        int a = swz(outb + 256 * j2);
        bre[a] = r[j2].x * scale;
        bim[a] = r[j2].y * scale;
    }
    __syncthreads();

    // tiled bf16 write: element (o=j, vp) -> B'[(j>>4)*HCOLS + vp][j&15] (4 B each)
    for (int j = t; j < FFT_N; j += 256) {
        int a = swz(j);
        outp[((size_t)(j >> 4) * HCOLS + vp) * 16 + (j & 15)] = packbf2(bre[a], bim[a]);
    }
}

// ---------------- pass 2: c2r IFFT over v, TWO rows per block ----------------
__global__ void __launch_bounds__(256) ifft_pass2_kernel(const unsigned* __restrict__ data,
                                                         __hip_bfloat16* __restrict__ wout) {
    __shared__ float bre[FFT_N];
    __shared__ float bim[FFT_N];
    const int t = threadIdx.x;
    const int bid = blockIdx.x;

    const int s = (bid & 7) * 256 + (bid >> 3);       // XCD-chunked
    const int o1 = 2 * s;
    const unsigned* __restrict__ gp = data + (size_t)(o1 >> 4) * HCOLS * 16 + (o1 & 15);

    for (int j = t; j < HCOLS; j += 256) {
        uint2 h = *reinterpret_cast<const uint2*>(gp + (size_t)j * 16);
        float h1r = bflo(h.x), h1i = bfhi(h.x);
        float h2r = bflo(h.y), h2i = bfhi(h.y);
        int a = swz(j & 4095);
        bre[a] = h1r - h2i; bim[a] = h1i + h2r;       // Z(j) = H1 + i*H2
        if (j != 0 && j != 2048) {
            int a2 = swz(4096 - j);                   // Z(-j) = conj(H1) + i*conj(H2)
            bre[a2] = h1r + h2i; bim[a2] = h2r - h1i;
        }
    }
    __syncthreads();

    const int rv[16] = {0, 8, 4, 12, 2, 10, 6, 14, 1, 9, 5, 13, 3, 11, 7, 15};
    float2 r[16];
    fft4096_lds(bre, bim, t, r, rv);

    const float scale = 1.0f / 4096.0f;
    const int k1 = t >> 4, lo = t & 15;
    const int outb = k1 + 16 * lo;
    #pragma unroll
    for (int j2 = 0; j2 < 16; ++j2) {
        int a = swz(outb + 256 * j2);
        bre[a] = r[j2].x * scale;                     // w[o1]
        bim[a] = r[j2].y * scale;                     // w[o2]
    }
    __syncthreads();

    __hip_bfloat16* __restrict__ out1 = wout + (size_t)o1 * FFT_N;
    __hip_bfloat16* __restrict__ out2 = wout + (size_t)(o1 + 1) * FFT_N;
    for (int j = t; j < FFT_N; j += 256) {
        int a = swz(j);
        out1[j] = __float2bfloat16(bre[a]);
        out2[j] = __float2bfloat16(bim[a]);
    }
}

// ---------------- bf16 MFMA GEMM (unchanged: BK=64, 3-buf, vmcnt(6)) ----------------
__device__ __forceinline__ void stage_tile(const __hip_bfloat16* __restrict__ X,
                                           const __hip_bfloat16* __restrict__ W,
                                           __hip_bfloat16* __restrict__ buf,
                                           int m0, int n0, int tt, int wv, int ln) {
    const int k0n = tt * 64;
    __hip_bfloat16* bufB = buf + 8192;
    #pragma unroll
    for (int kk = 0; kk < 2; ++kk) {
        const int s = kk * 512 + wv * 64 + ln;
        const int row = s >> 3;
        const int cc = (s & 7) ^ (row & 7);
        const __hip_bfloat16* g = X + (size_t)(m0 + row) * IN_F + k0n + cc * 8;
        __builtin_amdgcn_global_load_lds(
            (const __attribute__((address_space(1))) void*)g,
            (__attribute__((address_space(3))) void*)(buf + (size_t)(kk * 512 + wv * 64) * 8),
            16, 0, 0);
    }
    #pragma unroll
    for (int u = 0; u < 2; ++u)
        #pragma unroll
        for (int kk = 0; kk < 2; ++kk) {
            const int s = kk * 512 + wv * 64 + ln;
            const int row = u * 128 + (s >> 3);
            const int cc = (s & 7) ^ (row & 7);
            const __hip_bfloat16* g = W + (size_t)(n0 + row) * IN_F + k0n + cc * 8;
            __builtin_amdgcn_global_load_lds(
                (const __attribute__((address_space(1))) void*)g,
                (__attribute__((address_space(3))) void*)(bufB + (size_t)(u * 1024 + kk * 512 + wv * 64) * 8),
                16, 0, 0);
        }
}

__global__ void __launch_bounds__(512, 2) gemm_kernel(const __hip_bfloat16* __restrict__ X,
                                                      const __hip_bfloat16* __restrict__ W,
                                                      const float* __restrict__ bias,
                                                      float* __restrict__ out) {
    __shared__ __align__(16) __hip_bfloat16 smem[3 * 24576];   // 144 KB
    const int tid = threadIdx.x;
    const int wv = tid >> 6;        // wave 0..7
    const int ln = tid & 63;
    const int m0 = blockIdx.y * 128;
    const int n0 = blockIdx.x * 256;
    const int wm = wv >> 2, wn = wv & 3;
    const int r16 = ln & 15, kg = ln >> 4;
    const int x7 = ln & 7;

    f32x4 acc[4][4];
    #pragma unroll
    for (int i = 0; i < 4; ++i)
        #pragma unroll
        for (int j = 0; j < 4; ++j) acc[i][j] = (f32x4){0.f, 0.f, 0.f, 0.f};

    stage_tile(X, W, smem, m0, n0, 0, wv, ln);
    stage_tile(X, W, smem + 24576, m0, n0, 1, wv, ln);
    asm volatile("s_waitcnt vmcnt(6)" ::: "memory");   // tile 0 landed
    __builtin_amdgcn_s_barrier();

    for (int t = 0; t < 64; ++t) {
        const __hip_bfloat16* Ab = smem + (t % 3) * 24576;
        const __hip_bfloat16* Bb = Ab + 8192;

        // phase A: k-half-0 fragment reads only + prefetch issue for tile t+2
        bf16x8 a0[4], b0[4];
        #pragma unroll
        for (int i = 0; i < 4; ++i) {
            const int R = wm * 64 + i * 16 + r16;
            a0[i] = *reinterpret_cast<const bf16x8*>(Ab + R * 64 + ((kg ^ x7) << 3));
        }
        #pragma unroll
        for (int j = 0; j < 4; ++j) {
            const int R = wn * 64 + j * 16 + r16;
            b0[j] = *reinterpret_cast<const bf16x8*>(Bb + R * 64 + ((kg ^ x7) << 3));
        }
        if (t < 62)
            stage_tile(X, W, smem + ((t + 2) % 3) * 24576, m0, n0, t + 2, wv, ln);

        __builtin_amdgcn_s_barrier();                          // BAR(A)
        asm volatile("s_waitcnt lgkmcnt(0)" ::: "memory");
        __builtin_amdgcn_sched_barrier(0);
        __builtin_amdgcn_s_setprio(1);
        #pragma unroll
        for (int i = 0; i < 2; ++i)
            #pragma unroll
            for (int j = 0; j < 4; ++j)
                acc[i][j] = __builtin_amdgcn_mfma_f32_16x16x32_bf16(a0[i], b0[j], acc[i][j], 0, 0, 0);
        // issue k-half-1 reads; they interleave with the remaining 8 MFMAs
        bf16x8 a1[4], b1[4];
        #pragma unroll
        for (int i = 0; i < 4; ++i) {
            const int R = wm * 64 + i * 16 + r16;
            a1[i] = *reinterpret_cast<const bf16x8*>(Ab + R * 64 + (((4 | kg) ^ x7) << 3));
        }
        #pragma unroll
        for (int j = 0; j < 4; ++j) {
            const int R = wn * 64 + j * 16 + r16;
            b1[j] = *reinterpret_cast<const bf16x8*>(Bb + R * 64 + (((4 | kg) ^ x7) << 3));
        }
        #pragma unroll
        for (int i = 2; i < 4; ++i)
            #pragma unroll
            for (int j = 0; j < 4; ++j)
                acc[i][j] = __builtin_amdgcn_mfma_f32_16x16x32_bf16(a0[i], b0[j], acc[i][j], 0, 0, 0);
        __builtin_amdgcn_s_setprio(0);

        if (t < 62) {
            asm volatile("s_waitcnt vmcnt(6)" ::: "memory");
        } else if (t == 62) {
            asm volatile("s_waitcnt vmcnt(0)" ::: "memory");
        }
        __builtin_amdgcn_s_barrier();                          // BAR(B)
        asm volatile("s_waitcnt lgkmcnt(0)" ::: "memory");     // a1/b1 landed
        __builtin_amdgcn_sched_barrier(0);

        __builtin_amdgcn_s_setprio(1);
        #pragma unroll
        for (int i = 0; i < 4; ++i)
            #pragma unroll
            for (int j = 0; j < 4; ++j)
                acc[i][j] = __builtin_amdgcn_mfma_f32_16x16x32_bf16(a1[i], b1[j], acc[i][j], 0, 0, 0);
        __builtin_amdgcn_s_setprio(0);
    }

    // epilogue: D[m][n], n = lane&15, m = (lane>>4)*4 + e
    #pragma unroll
    for (int i = 0; i < 4; ++i)
        #pragma unroll
        for (int j = 0; j < 4; ++j) {
            const int n = n0 + wn * 64 + j * 16 + r16;
            const float bs = bias[n];
            #pragma unroll
            for (int e = 0; e < 4; ++e) {
                const int m = m0 + wm * 64 + i * 16 + kg * 4 + e;
                out[(size_t)m * OUT_F + n] = acc[i][j][e] + bs;
            }
        }
}

extern "C" void kernel_launch(void* const* d_in, const int* in_sizes, int n_in,
                              void* d_out, int out_size, void* d_ws, size_t ws_size,
                              hipStream_t stream) {
    const float* x    = (const float*)d_in[0];
    const float* sre  = (const float*)d_in[1];
    const float* sim  = (const float*)d_in[2];
    const int*   sidx = (const int*)d_in[3];
    const float* bias = (const float*)d_in[4];
    const int nnz = in_sizes[1];
    float* out = (float*)d_out;

    char* ws = (char*)d_ws;
    // A (tiled bf16-packed intermediate, 256 panels x 2049 x 16 u32 = 33.6 MB) @ 0
    unsigned* A = (unsigned*)ws;
    // sharded bucket entries @ 128 MiB (64 MiB); dead before pass2 writes Wb
    uint4* bkt = (uint4*)(ws + 134217728);
    __hip_bfloat16* Wb = (__hip_bfloat16*)(ws + 134217728);               // 33.5 MB (pass2 out)
    __hip_bfloat16* Xb = (__hip_bfloat16*)(ws + 67108864);                // 16.8 MB
    unsigned* pos = (unsigned*)(ws + 100663296);                          // 2 MB (padded, sharded)

    hipMemsetAsync(pos, 0, (size_t)4096 * SHARDS * 16 * sizeof(unsigned), stream);

    const int sb = (nnz + 255) / 256;
    // scatter blocks + 512 cast blocks (independent work overlapped)
    bucket_scatter_kernel<<<sb + 512, 256, 0, stream>>>(sidx, sre, sim, pos, bkt, nnz, sb,
                                                        (const float4*)x, (ushort4*)Xb);

    // pass 1: Hermitian-symmetrized scatter + IFFT over u; columns 0..2048 only
    ifft_pass1_kernel<<<HCOLS, 256, 0, stream>>>(pos, bkt, A);
    // pass 2: c2r IFFT over v, two rows per block -> bf16 weight
    ifft_pass2_kernel<<<FFT_N / 2, 256, 0, stream>>>(A, Wb);

    gemm_kernel<<<dim3(OUT_F / 256, MROWS / 128), 512, 0, stream>>>(Xb, Wb, bias, out);
}

// Round 17
// 177.014 us; speedup vs baseline: 1.0593x; 1.0593x over previous
//
#include <hip/hip_runtime.h>
#include <hip/hip_bf16.h>

#define OUT_F 4096
#define IN_F 4096
#define MROWS 2048            // 4*512 batch rows
#define FFT_N 4096
#define HCOLS 2049            // Hermitian-reduced column count
#define BCAP 1024             // fixed bucket capacity (expected max ~263)
#define PSTRIDE 16            // pos counter stride: 1 counter per 64-B line

typedef short bf16x8 __attribute__((ext_vector_type(8)));
typedef float f32x4 __attribute__((ext_vector_type(4)));

// ====== bucket build (+ fused x-cast): blocks [0,sb) scatter, [sb,sb+512) cast ======
// 8 entries per thread with INDEPENDENT atomicAdds issued back-to-back (8 in
// flight per lane) -> hides the ~1k-cycle L3 atomic round-trip that a
// 1-entry-per-thread kernel pays serially (VALUBusy was 0.8%).
__global__ void bucket_scatter_kernel(const int* __restrict__ idx, const float* __restrict__ re,
                                      const float* __restrict__ im, unsigned* __restrict__ pos,
                                      uint4* __restrict__ bkt, int nnz, int sb,
                                      const float4* __restrict__ x, ushort4* __restrict__ xb) {
    const int bid = blockIdx.x;
    const int t = threadIdx.x;
    if (bid >= sb) {                                  // cast branch (independent work)
        const int n4 = MROWS * IN_F / 4;
        const int stride = 512 * 256;
        for (int i = (bid - sb) * 256 + t; i < n4; i += stride) {
            float4 v = x[i];
            __hip_bfloat16 a = __float2bfloat16(v.x);
            __hip_bfloat16 b = __float2bfloat16(v.y);
            __hip_bfloat16 c = __float2bfloat16(v.z);
            __hip_bfloat16 d = __float2bfloat16(v.w);
            ushort4 o;
            o.x = *reinterpret_cast<unsigned short*>(&a);
            o.y = *reinterpret_cast<unsigned short*>(&b);
            o.z = *reinterpret_cast<unsigned short*>(&c);
            o.w = *reinterpret_cast<unsigned short*>(&d);
            xb[i] = o;
        }
        return;
    }
    const int kbase = bid * 2048 + t;                 // 8 coalesced chunks of 256
    int kk[8]; int id[8]; float rv[8], iv[8]; bool val[8]; unsigned p[8];
    #pragma unroll
    for (int e = 0; e < 8; ++e) {
        int k = kbase + e * 256;
        val[e] = (k < nnz);
        kk[e] = val[e] ? k : 0;
        id[e] = val[e] ? idx[kk[e]] : 0;
        rv[e] = val[e] ? re[kk[e]] : 0.f;
        iv[e] = val[e] ? im[kk[e]] : 0.f;
    }
    #pragma unroll
    for (int e = 0; e < 8; ++e) {                     // 8 independent RMWs in flight
        unsigned v = (unsigned)id[e] & (IN_F - 1);
        p[e] = val[e] ? atomicAdd(&pos[v * PSTRIDE], 1u) : 0u;
    }
    #pragma unroll
    for (int e = 0; e < 8; ++e) {
        if (val[e] && p[e] < BCAP) {
            unsigned v = (unsigned)id[e] & (IN_F - 1);
            unsigned u = (unsigned)id[e] >> 12;
            bkt[v * BCAP + p[e]] = make_uint4(((unsigned)kk[e] << 12) | u,
                                              __float_as_uint(rv[e]),
                                              __float_as_uint(iv[e]), 0u);
        }
    }
}

// ================= 16-pt inverse FFT building blocks =================
__device__ __forceinline__ float2 cmul(float2 a, float2 b) {
    return make_float2(a.x * b.x - a.y * b.y, a.x * b.y + a.y * b.x);
}
__device__ __forceinline__ void bflyw(float2& a, float2& b, float wr, float wi) {
    float tr = b.x * wr - b.y * wi;
    float ti = b.x * wi + b.y * wr;
    b.x = a.x - tr; b.y = a.y - ti;
    a.x += tr; a.y += ti;
}
__device__ __forceinline__ void bfly1(float2& a, float2& b) {   // w = 1
    float tr = b.x, ti = b.y;
    b.x = a.x - tr; b.y = a.y - ti;
    a.x += tr; a.y += ti;
}
__device__ __forceinline__ void bflyI(float2& a, float2& b) {   // w = +i
    float tr = -b.y, ti = b.x;
    b.x = a.x - tr; b.y = a.y - ti;
    a.x += tr; a.y += ti;
}

#define C8f  0.70710678118654752f
#define C16f 0.92387953251128676f
#define S16f 0.38268343236508977f

// inverse 16-pt FFT (+i convention). Input in bit-reversed slots, output natural.
__device__ __forceinline__ void fft16(float2 r[16]) {
    bfly1(r[0], r[1]);  bfly1(r[2], r[3]);  bfly1(r[4], r[5]);   bfly1(r[6], r[7]);
    bfly1(r[8], r[9]);  bfly1(r[10], r[11]); bfly1(r[12], r[13]); bfly1(r[14], r[15]);
    bfly1(r[0], r[2]);  bflyI(r[1], r[3]);
    bfly1(r[4], r[6]);  bflyI(r[5], r[7]);
    bfly1(r[8], r[10]); bflyI(r[9], r[11]);
    bfly1(r[12], r[14]); bflyI(r[13], r[15]);
    bfly1(r[0], r[4]);  bflyw(r[1], r[5], C8f, C8f);  bflyI(r[2], r[6]);  bflyw(r[3], r[7], -C8f, C8f);
    bfly1(r[8], r[12]); bflyw(r[9], r[13], C8f, C8f); bflyI(r[10], r[14]); bflyw(r[11], r[15], -C8f, C8f);
    bfly1(r[0], r[8]);
    bflyw(r[1], r[9],  C16f, S16f);
    bflyw(r[2], r[10], C8f,  C8f);
    bflyw(r[3], r[11], S16f, C16f);
    bflyI(r[4], r[12]);
    bflyw(r[5], r[13], -S16f, C16f);
    bflyw(r[6], r[14], -C8f,  C8f);
    bflyw(r[7], r[15], -C16f, S16f);
}

// depth-4 tree twiddle: r[k] *= w^k, w = exp(i*ang).
__device__ __forceinline__ void twiddle16(float2 r[16], float ang) {
    float s, c;
    __sincosf(ang, &s, &c);
    float2 w1 = make_float2(c, s);
    float2 w2 = cmul(w1, w1), w4 = cmul(w2, w2), w8 = cmul(w4, w4);
    float2 cur[16];
    cur[1] = w1; cur[2] = w2; cur[3] = cmul(w2, w1);
    cur[4] = w4; cur[5] = cmul(w4, w1); cur[6] = cmul(w4, w2); cur[7] = cmul(w4, cur[3]);
    #pragma unroll
    for (int k = 0; k < 8; ++k) cur[8 + k] = (k == 0) ? w8 : cmul(w8, cur[k]);
    #pragma unroll
    for (int k = 1; k < 16; ++k) r[k] = cmul(r[k], cur[k]);
}

// LDS XOR swizzle: bijective on [0,4096)
__device__ __forceinline__ int swz(int a) { return a ^ ((a >> 5) & 31); }

__device__ __forceinline__ unsigned packbf2(float re, float im) {
    __hip_bfloat16 r = __float2bfloat16(re), i = __float2bfloat16(im);
    unsigned short rb = *reinterpret_cast<unsigned short*>(&r);
    unsigned short ib = *reinterpret_cast<unsigned short*>(&i);
    return ((unsigned)ib << 16) | (unsigned)rb;
}
__device__ __forceinline__ float bflo(unsigned p) { return __uint_as_float(p << 16); }
__device__ __forceinline__ float bfhi(unsigned p) { return __uint_as_float(p & 0xffff0000u); }

__device__ __forceinline__ void fft4096_lds(float* bre, float* bim, int t, float2 r[16],
                                            const int* rv) {
    // ---- phase 1: 16-pt over n1, column n2 = t ----
    #pragma unroll
    for (int n1 = 0; n1 < 16; ++n1) {
        int a = swz(256 * n1 + t);
        r[rv[n1]] = make_float2(bre[a], bim[a]);
    }
    fft16(r);
    twiddle16(r, (float)t * 1.5339807878856412e-3f);   // 2*pi/4096
    #pragma unroll
    for (int k = 0; k < 16; ++k) {
        int a = swz(256 * k + t);
        bre[a] = r[k].x; bim[a] = r[k].y;
    }
    __syncthreads();

    // ---- phase 2 ----
    const int k1 = t >> 4;
    const int lo = t & 15;
    const int base2 = 256 * k1 + lo;
    #pragma unroll
    for (int m1 = 0; m1 < 16; ++m1) {
        int a = swz(base2 + 16 * m1);
        r[rv[m1]] = make_float2(bre[a], bim[a]);
    }
    fft16(r);
    twiddle16(r, (float)lo * 2.45436926061702596e-2f); // 2*pi/256
    #pragma unroll
    for (int k = 0; k < 16; ++k) {
        int a = swz(base2 + 16 * k);
        bre[a] = r[k].x; bim[a] = r[k].y;
    }
    __syncthreads();

    // ---- phase 3 ----
    const int base3 = 256 * k1 + 16 * lo;
    #pragma unroll
    for (int m = 0; m < 16; ++m) {
        int a = swz(base3 + m);
        r[rv[m]] = make_float2(bre[a], bim[a]);
    }
    fft16(r);
    __syncthreads();   // all reads done before digit-swap scatter overwrites
}

// ---------------- pass 1: Hermitian-symmetrized scatter + 4096-pt IFFT over u ----------------
__global__ void __launch_bounds__(256) ifft_pass1_kernel(const unsigned* __restrict__ pos,
                                                         const uint4* __restrict__ bkt,
                                                         unsigned* __restrict__ outp) {
    __shared__ float bre[FFT_N];
    __shared__ float bim[FFT_N];
    unsigned* kwin  = (unsigned*)bre;   // alias: dead before bre is zero-filled
    unsigned* kwin2 = (unsigned*)bim;
    const int t = threadIdx.x;
    const int vp = blockIdx.x;                 // 0..2048
    const int bd = vp;
    const int bm = (4096 - vp) & 4095;         // mirror bucket (== bd for vp=0,2048)
    const bool sameb = (bm == bd);

    const unsigned cd = min(pos[bd * PSTRIDE], (unsigned)BCAP);
    const unsigned cm = min(pos[bm * PSTRIDE], (unsigned)BCAP);
    const unsigned b0d = (unsigned)bd * BCAP, b0m = (unsigned)bm * BCAP;

    unsigned pkD[4], pkM[4]; float2 wvD[4], wvM[4];
    bool vldD[4], vldM[4], winD[4], winM[4];
    #pragma unroll
    for (int e = 0; e < 4; ++e) {
        unsigned o = (unsigned)t + 256u * (unsigned)e;
        vldD[e] = (o < cd);
        uint4 eD = vldD[e] ? bkt[b0d + o] : make_uint4(0u, 0u, 0u, 0u);
        pkD[e] = eD.x;
        wvD[e] = make_float2(__uint_as_float(eD.y), __uint_as_float(eD.z));
        vldM[e] = (o < cm);
        uint4 eM = vldM[e] ? bkt[b0m + o] : make_uint4(0u, 0u, 0u, 0u);
        pkM[e] = eM.x;
        wvM[e] = make_float2(__uint_as_float(eM.y), __uint_as_float(eM.z));
    }

    // single-round winner resolution: D -> kwin, M -> kwin2 (vectorized zero)
    {
        uint4 z4 = make_uint4(0u, 0u, 0u, 0u);
        uint4* kz1 = (uint4*)kwin;
        uint4* kz2 = (uint4*)kwin2;
        #pragma unroll
        for (int j = 0; j < 4; ++j) { kz1[t + j * 256] = z4; kz2[t + j * 256] = z4; }
    }
    __syncthreads();
    #pragma unroll
    for (int e = 0; e < 4; ++e)
        if (vldD[e]) atomicMax(&kwin[pkD[e] & 4095u], pkD[e]);
    #pragma unroll
    for (int e = 0; e < 4; ++e)
        if (vldM[e]) atomicMax(&kwin2[pkM[e] & 4095u], pkM[e]);
    __syncthreads();
    #pragma unroll
    for (int e = 0; e < 4; ++e)
        winD[e] = vldD[e] && (kwin[pkD[e] & 4095u] == pkD[e]);
    #pragma unroll
    for (int e = 0; e < 4; ++e)
        winM[e] = vldM[e] && ((sameb ? kwin : kwin2)[pkM[e] & 4095u] == pkM[e]);
    __syncthreads();   // all kwin reads done before bre/bim overwrite

    {
        float4 z4 = make_float4(0.f, 0.f, 0.f, 0.f);
        float4* z1 = (float4*)bre;
        float4* z2 = (float4*)bim;
        #pragma unroll
        for (int j = 0; j < 4; ++j) { z1[t + j * 256] = z4; z2[t + j * 256] = z4; }
    }
    __syncthreads();
    // merged scatter: D adds 0.5*val at u, M adds 0.5*conj(val) at 4096-u2.
    // <=1 D-adder and <=1 M-adder per cell; commutative adds -> deterministic.
    #pragma unroll
    for (int e = 0; e < 4; ++e)
        if (winD[e]) {
            int a = swz((int)(pkD[e] & 4095u));
            atomicAdd(&bre[a], 0.5f * wvD[e].x);
            atomicAdd(&bim[a], 0.5f * wvD[e].y);
        }
    #pragma unroll
    for (int e = 0; e < 4; ++e)
        if (winM[e]) {
            int u2 = (int)(pkM[e] & 4095u);
            int a = swz((4096 - u2) & 4095);
            atomicAdd(&bre[a], 0.5f * wvM[e].x);
            atomicAdd(&bim[a], -0.5f * wvM[e].y);
        }
    __syncthreads();

    const int rv[16] = {0, 8, 4, 12, 2, 10, 6, 14, 1, 9, 5, 13, 3, 11, 7, 15};
    float2 r[16];
    fft4096_lds(bre, bim, t, r, rv);

    const float scale = 1.0f / 4096.0f;
    const int k1 = t >> 4, lo = t & 15;
    const int outb = k1 + 16 * lo;
    #pragma unroll
    for (int j2 = 0; j2 < 16; ++j2) {
        int a = swz(outb + 256 * j2);
        bre[a] = r[j2].x * scale;
        bim[a] = r[j2].y * scale;
    }
    __syncthreads();

    // tiled bf16 write: element (o=j, vp) -> B'[(j>>4)*HCOLS + vp][j&15] (4 B each)
    for (int j = t; j < FFT_N; j += 256) {
        int a = swz(j);
        outp[((size_t)(j >> 4) * HCOLS + vp) * 16 + (j & 15)] = packbf2(bre[a], bim[a]);
    }
}

// ---------------- pass 2: c2r IFFT over v, TWO rows per block ----------------
__global__ void __launch_bounds__(256) ifft_pass2_kernel(const unsigned* __restrict__ data,
                                                         __hip_bfloat16* __restrict__ wout) {
    __shared__ float bre[FFT_N];
    __shared__ float bim[FFT_N];
    const int t = threadIdx.x;
    const int bid = blockIdx.x;

    const int s = (bid & 7) * 256 + (bid >> 3);       // XCD-chunked
    const int o1 = 2 * s;
    const unsigned* __restrict__ gp = data + (size_t)(o1 >> 4) * HCOLS * 16 + (o1 & 15);

    for (int j = t; j < HCOLS; j += 256) {
        uint2 h = *reinterpret_cast<const uint2*>(gp + (size_t)j * 16);
        float h1r = bflo(h.x), h1i = bfhi(h.x);
        float h2r = bflo(h.y), h2i = bfhi(h.y);
        int a = swz(j & 4095);
        bre[a] = h1r - h2i; bim[a] = h1i + h2r;       // Z(j) = H1 + i*H2
        if (j != 0 && j != 2048) {
            int a2 = swz(4096 - j);                   // Z(-j) = conj(H1) + i*conj(H2)
            bre[a2] = h1r + h2i; bim[a2] = h2r - h1i;
        }
    }
    __syncthreads();

    const int rv[16] = {0, 8, 4, 12, 2, 10, 6, 14, 1, 9, 5, 13, 3, 11, 7, 15};
    float2 r[16];
    fft4096_lds(bre, bim, t, r, rv);

    const float scale = 1.0f / 4096.0f;
    const int k1 = t >> 4, lo = t & 15;
    const int outb = k1 + 16 * lo;
    #pragma unroll
    for (int j2 = 0; j2 < 16; ++j2) {
        int a = swz(outb + 256 * j2);
        bre[a] = r[j2].x * scale;                     // w[o1]
        bim[a] = r[j2].y * scale;                     // w[o2]
    }
    __syncthreads();

    __hip_bfloat16* __restrict__ out1 = wout + (size_t)o1 * FFT_N;
    __hip_bfloat16* __restrict__ out2 = wout + (size_t)(o1 + 1) * FFT_N;
    for (int j = t; j < FFT_N; j += 256) {
        int a = swz(j);
        out1[j] = __float2bfloat16(bre[a]);
        out2[j] = __float2bfloat16(bim[a]);
    }
}

// ---------------- bf16 MFMA GEMM (unchanged: BK=64, 3-buf, vmcnt(6)) ----------------
__device__ __forceinline__ void stage_tile(const __hip_bfloat16* __restrict__ X,
                                           const __hip_bfloat16* __restrict__ W,
                                           __hip_bfloat16* __restrict__ buf,
                                           int m0, int n0, int tt, int wv, int ln) {
    const int k0n = tt * 64;
    __hip_bfloat16* bufB = buf + 8192;
    #pragma unroll
    for (int kk = 0; kk < 2; ++kk) {
        const int s = kk * 512 + wv * 64 + ln;
        const int row = s >> 3;
        const int cc = (s & 7) ^ (row & 7);
        const __hip_bfloat16* g = X + (size_t)(m0 + row) * IN_F + k0n + cc * 8;
        __builtin_amdgcn_global_load_lds(
            (const __attribute__((address_space(1))) void*)g,
            (__attribute__((address_space(3))) void*)(buf + (size_t)(kk * 512 + wv * 64) * 8),
            16, 0, 0);
    }
    #pragma unroll
    for (int u = 0; u < 2; ++u)
        #pragma unroll
        for (int kk = 0; kk < 2; ++kk) {
            const int s = kk * 512 + wv * 64 + ln;
            const int row = u * 128 + (s >> 3);
            const int cc = (s & 7) ^ (row & 7);
            const __hip_bfloat16* g = W + (size_t)(n0 + row) * IN_F + k0n + cc * 8;
            __builtin_amdgcn_global_load_lds(
                (const __attribute__((address_space(1))) void*)g,
                (__attribute__((address_space(3))) void*)(bufB + (size_t)(u * 1024 + kk * 512 + wv * 64) * 8),
                16, 0, 0);
        }
}

__global__ void __launch_bounds__(512, 2) gemm_kernel(const __hip_bfloat16* __restrict__ X,
                                                      const __hip_bfloat16* __restrict__ W,
                                                      const float* __restrict__ bias,
                                                      float* __restrict__ out) {
    __shared__ __align__(16) __hip_bfloat16 smem[3 * 24576];   // 144 KB
    const int tid = threadIdx.x;
    const int wv = tid >> 6;        // wave 0..7
    const int ln = tid & 63;
    const int m0 = blockIdx.y * 128;
    const int n0 = blockIdx.x * 256;
    const int wm = wv >> 2, wn = wv & 3;
    const int r16 = ln & 15, kg = ln >> 4;
    const int x7 = ln & 7;

    f32x4 acc[4][4];
    #pragma unroll
    for (int i = 0; i < 4; ++i)
        #pragma unroll
        for (int j = 0; j < 4; ++j) acc[i][j] = (f32x4){0.f, 0.f, 0.f, 0.f};

    stage_tile(X, W, smem, m0, n0, 0, wv, ln);
    stage_tile(X, W, smem + 24576, m0, n0, 1, wv, ln);
    asm volatile("s_waitcnt vmcnt(6)" ::: "memory");   // tile 0 landed
    __builtin_amdgcn_s_barrier();

    for (int t = 0; t < 64; ++t) {
        const __hip_bfloat16* Ab = smem + (t % 3) * 24576;
        const __hip_bfloat16* Bb = Ab + 8192;

        // phase A: k-half-0 fragment reads only + prefetch issue for tile t+2
        bf16x8 a0[4], b0[4];
        #pragma unroll
        for (int i = 0; i < 4; ++i) {
            const int R = wm * 64 + i * 16 + r16;
            a0[i] = *reinterpret_cast<const bf16x8*>(Ab + R * 64 + ((kg ^ x7) << 3));
        }
        #pragma unroll
        for (int j = 0; j < 4; ++j) {
            const int R = wn * 64 + j * 16 + r16;
            b0[j] = *reinterpret_cast<const bf16x8*>(Bb + R * 64 + ((kg ^ x7) << 3));
        }
        if (t < 62)
            stage_tile(X, W, smem + ((t + 2) % 3) * 24576, m0, n0, t + 2, wv, ln);

        __builtin_amdgcn_s_barrier();                          // BAR(A)
        asm volatile("s_waitcnt lgkmcnt(0)" ::: "memory");
        __builtin_amdgcn_sched_barrier(0);
        __builtin_amdgcn_s_setprio(1);
        #pragma unroll
        for (int i = 0; i < 2; ++i)
            #pragma unroll
            for (int j = 0; j < 4; ++j)
                acc[i][j] = __builtin_amdgcn_mfma_f32_16x16x32_bf16(a0[i], b0[j], acc[i][j], 0, 0, 0);
        // issue k-half-1 reads; they interleave with the remaining 8 MFMAs
        bf16x8 a1[4], b1[4];
        #pragma unroll
        for (int i = 0; i < 4; ++i) {
            const int R = wm * 64 + i * 16 + r16;
            a1[i] = *reinterpret_cast<const bf16x8*>(Ab + R * 64 + (((4 | kg) ^ x7) << 3));
        }
        #pragma unroll
        for (int j = 0; j < 4; ++j) {
            const int R = wn * 64 + j * 16 + r16;
            b1[j] = *reinterpret_cast<const bf16x8*>(Bb + R * 64 + (((4 | kg) ^ x7) << 3));
        }
        #pragma unroll
        for (int i = 2; i < 4; ++i)
            #pragma unroll
            for (int j = 0; j < 4; ++j)
                acc[i][j] = __builtin_amdgcn_mfma_f32_16x16x32_bf16(a0[i], b0[j], acc[i][j], 0, 0, 0);
        __builtin_amdgcn_s_setprio(0);

        if (t < 62) {
            asm volatile("s_waitcnt vmcnt(6)" ::: "memory");
        } else if (t == 62) {
            asm volatile("s_waitcnt vmcnt(0)" ::: "memory");
        }
        __builtin_amdgcn_s_barrier();                          // BAR(B)
        asm volatile("s_waitcnt lgkmcnt(0)" ::: "memory");     // a1/b1 landed
        __builtin_amdgcn_sched_barrier(0);

        __builtin_amdgcn_s_setprio(1);
        #pragma unroll
        for (int i = 0; i < 4; ++i)
            #pragma unroll
            for (int j = 0; j < 4; ++j)
                acc[i][j] = __builtin_amdgcn_mfma_f32_16x16x32_bf16(a1[i], b1[j], acc[i][j], 0, 0, 0);
        __builtin_amdgcn_s_setprio(0);
    }

    // epilogue: D[m][n], n = lane&15, m = (lane>>4)*4 + e
    #pragma unroll
    for (int i = 0; i < 4; ++i)
        #pragma unroll
        for (int j = 0; j < 4; ++j) {
            const int n = n0 + wn * 64 + j * 16 + r16;
            const float bs = bias[n];
            #pragma unroll
            for (int e = 0; e < 4; ++e) {
                const int m = m0 + wm * 64 + i * 16 + kg * 4 + e;
                out[(size_t)m * OUT_F + n] = acc[i][j][e] + bs;
            }
        }
}

extern "C" void kernel_launch(void* const* d_in, const int* in_sizes, int n_in,
                              void* d_out, int out_size, void* d_ws, size_t ws_size,
                              hipStream_t stream) {
    const float* x    = (const float*)d_in[0];
    const float* sre  = (const float*)d_in[1];
    const float* sim  = (const float*)d_in[2];
    const int*   sidx = (const int*)d_in[3];
    const float* bias = (const float*)d_in[4];
    const int nnz = in_sizes[1];
    float* out = (float*)d_out;

    char* ws = (char*)d_ws;
    // A (tiled bf16-packed intermediate, 256 panels x 2049 x 16 u32 = 33.6 MB) @ 0
    unsigned* A = (unsigned*)ws;
    // bucket entries @ 128 MiB (67.1 MB); dead before pass2 writes Wb
    uint4* bkt = (uint4*)(ws + 134217728);
    __hip_bfloat16* Wb = (__hip_bfloat16*)(ws + 134217728);               // 33.5 MB (pass2 out)
    __hip_bfloat16* Xb = (__hip_bfloat16*)(ws + 67108864);                // 16.8 MB
    unsigned* pos = (unsigned*)(ws + 100663296);                          // 256 KB (padded)

    hipMemsetAsync(pos, 0, 4096 * PSTRIDE * sizeof(unsigned), stream);

    const int sb = (nnz + 2047) / 2048;   // 8 entries per thread
    // scatter blocks + 512 cast blocks (independent work overlapped)
    bucket_scatter_kernel<<<sb + 512, 256, 0, stream>>>(sidx, sre, sim, pos, bkt, nnz, sb,
                                                        (const float4*)x, (ushort4*)Xb);

    // pass 1: Hermitian-symmetrized scatter + IFFT over u; columns 0..2048 only
    ifft_pass1_kernel<<<HCOLS, 256, 0, stream>>>(pos, bkt, A);
    // pass 2: c2r IFFT over v, two rows per block -> bf16 weight
    ifft_pass2_kernel<<<FFT_N / 2, 256, 0, stream>>>(A, Wb);

    gemm_kernel<<<dim3(OUT_F / 256, MROWS / 128), 512, 0, stream>>>(Xb, Wb, bias, out);
}